// Round 7
// baseline (276.493 us; speedup 1.0000x reference)
//
#include <hip/hip_runtime.h>
#include <hip/hip_cooperative_groups.h>

namespace cg = cooperative_groups;

#define BATCH 8192
#define NG 3
#define NE 32
#define D 128
#define NPAIR (BATCH * NG)            // 24576
#define TILE 32                       // tokens per GEMM tile
#define MAXT (NPAIR / TILE + NE - 1)  // 799 worst-case tiles
#define NHB (NPAIR / 256)             // 96 hist/scatter blocks
#define NFIN (BATCH * 16 / 256)       // 512 final units

typedef __attribute__((ext_vector_type(8))) short short8;
typedef __attribute__((ext_vector_type(4))) float f32x4;

// ---------------- workspace layout (bytes) ----------------
#define OFF_NT     0                      // int
#define OFF_TILES  256                    // int4[MAXT] = 12784
#define OFF_HISTPB 16384                  // int[96][32] = 12288
#define OFF_PAIR   32768                  // int[NPAIR] = 98304 -> ends 131072
#define OFF_WT0    131072                 // swizzled bf16 W0^T, 1 MB
#define OFF_WT1    (OFF_WT0 + (size_t)NE * D * D * 2)
#define OFF_YB     (OFF_WT1 + (size_t)NE * D * D * 2)    // bf16 [NPAIR][D], 6 MB
#define OFF_YB2    (OFF_YB  + (size_t)NPAIR * D * 2)     // bf16 [NPAIR][D], 6 MB
#define WS_REQUIRED (OFF_YB2 + (size_t)NPAIR * D * 2)    // ~14.8 MB

static __device__ __forceinline__ ushort f2bf(float f) {
    unsigned b = __float_as_uint(f);
    unsigned r = (b + 0x7FFFu + ((b >> 16) & 1u)) >> 16;   // RNE
    return (ushort)r;
}
static __device__ __forceinline__ float bf2f(ushort u) {
    return __uint_as_float(((unsigned)u) << 16);
}
static __device__ __forceinline__ unsigned pk2(float lo, float hi) {
    return (unsigned)f2bf(lo) | ((unsigned)f2bf(hi) << 16);
}

// global -> LDS direct copy, 16 B per lane. LDS base wave-uniform; HW writes
// ldsbase + lane*16. Global ptr is per-lane.
static __device__ __forceinline__ void gl_lds16(const void* g, void* l) {
    __builtin_amdgcn_global_load_lds(
        (const __attribute__((address_space(1))) void*)g,
        (__attribute__((address_space(3))) void*)l, 16, 0, 0);
}

// ================= shared phase bodies =================

// W transpose unit u (0..127): 64 cols of one matrix -> swizzled bf16 Wt.
static __device__ __forceinline__ void transpose_unit(
    int u, int tid, char* smem, const float* __restrict__ W0,
    const float* __restrict__ W1, ushort* __restrict__ Wt0,
    ushort* __restrict__ Wt1)
{
    ushort* sT = (ushort*)smem;    // [128][68] ushort, byte stride 136
    const int m = u >> 1, hcol = u & 1;
    const float* Ws = ((m < 32) ? W0 : W1) + (size_t)(m & 31) * D * D;
    ushort* Wte = ((m < 32) ? Wt0 : Wt1) + (size_t)(m & 31) * D * D;

    #pragma unroll
    for (int i = 0; i < 8; ++i) {         // read [k][col-half] coalesced
        int f4 = tid + i * 256;
        int k = f4 >> 4, c4 = f4 & 15;
        float4 f = *(const float4*)&Ws[(size_t)k * D + hcol * 64 + c4 * 4];
        ushort4 p = { f2bf(f.x), f2bf(f.y), f2bf(f.z), f2bf(f.w) };
        *(ushort4*)&sT[k * 68 + c4 * 4] = p;
    }
    __syncthreads();
    #pragma unroll
    for (int i = 0; i < 4; ++i) {         // write [col][k], swizzled dest
        int f = tid + i * 256;
        int cl = f >> 4, k0 = (f & 15) * 8;
        int col = hcol * 64 + cl;
        ushort u8[8];
        #pragma unroll
        for (int j = 0; j < 8; ++j) u8[j] = sT[(k0 + j) * 68 + cl];
        ushort4 q0 = { u8[0], u8[1], u8[2], u8[3] };
        ushort4 q1 = { u8[4], u8[5], u8[6], u8[7] };
        int byteoff = (col * 256 + k0 * 2) ^ ((col & 7) << 4);
        *(ushort4*)((char*)Wte + byteoff)     = q0;
        *(ushort4*)((char*)Wte + byteoff + 8) = q1;
    }
}

static __device__ __forceinline__ void hist_unit(
    int h, int tid, char* smem, const int* __restrict__ genres,
    int* __restrict__ hist_pb)
{
    int* sh = (int*)smem;
    if (tid < NE) sh[tid] = 0;
    __syncthreads();
    int g = genres[h * 256 + tid];
    if (g != 0) atomicAdd(&sh[g], 1);
    __syncthreads();
    if (tid < NE) hist_pb[h * NE + tid] = sh[tid];
}

// scatter unit p; unit 0 also emits the tile list. Within-bucket order is
// scheduling-dependent, but y is indexed by pair id -> output invariant.
static __device__ __forceinline__ void scatter_unit(
    int p, int tid, char* smem, const int* __restrict__ genres,
    const int* __restrict__ hist_pb, int* __restrict__ pair_bg,
    int* __restrict__ nTiles, int4* __restrict__ tileInfo)
{
    int* sbase = (int*)smem;
    int* scur  = (int*)(smem + 128);
    if (tid < NE) {
        int tot = 0, pre = 0;
        for (int h = 0; h < NHB; ++h) {
            int c = hist_pb[h * NE + tid];
            tot += c;
            if (h < p) pre += c;
        }
        int off = 0;
        for (int j = 0; j < NE; ++j) {
            int tj = __shfl(tot, j, 64);
            if (j < tid) off += tj;
        }
        sbase[tid] = off + pre;
        scur[tid] = 0;
        if (p == 0) {
            int ntl = (tot + TILE - 1) / TILE;
            int tbase = 0, ttot = 0;
            for (int j = 0; j < NE; ++j) {
                int nj = __shfl(ntl, j, 64);
                if (j < tid) tbase += nj;
                ttot += nj;
            }
            if (tid == 0) *nTiles = ttot;
            for (int t = 0; t < ntl; ++t) {
                int rem = tot - t * TILE;
                tileInfo[tbase + t] =
                    make_int4(tid, off + t * TILE, (rem < TILE) ? rem : TILE, 0);
            }
        }
    }
    __syncthreads();
    const int i = p * 256 + tid;
    const int g = genres[i];
    if (g != 0) {
        int r = atomicAdd(&scur[g], 1);
        pair_bg[sbase[g] + r] = i;
    }
}

// One GEMM tile: ydst[pair] = staged_x @ Wt[e]. LAYER 1 stages x from f32
// with fused bf16+1/cnt scale; LAYER 2 stages lrelu(sum slots yb)/cnt.
template<int LAYER>
static __device__ __forceinline__ void gemm_tile_body(
    char* sWb, char* sXb,
    const float* __restrict__ x, const ushort* __restrict__ ybin,
    const int* __restrict__ genres, const ushort* __restrict__ Wt,
    const int* __restrict__ pair_bg,
    int e, int start, int nt, ushort* __restrict__ ydst, int tid)
{
    const int wave = tid >> 6, lane = tid & 63;

    // stage W: linear 16B DMA of the pre-swizzled tile
    const char* wsrc = (const char*)(Wt + (size_t)e * D * D);
    #pragma unroll
    for (int i = 0; i < 8; ++i) {
        int c = wave * 8 + i;
        gl_lds16(wsrc + c * 1024 + lane * 16, sWb + c * 1024);
    }

    // stage x: 8 threads per token, 16 cols each
    {
        const int t = tid >> 3, th = tid & 7;
        int bg = pair_bg[start + ((t < nt) ? t : 0)];
        int row = bg / NG;
        int g0 = genres[row * NG + 0];
        int g1 = genres[row * NG + 1];
        int g2 = genres[row * NG + 2];
        int cnt = (g0 != 0) + (g1 != 0) + (g2 != 0);
        float scale = 1.0f / (float)((cnt > 0) ? cnt : 1);
        unsigned q[8];
        if (LAYER == 1) {
            const float* xp = x + (size_t)row * D + th * 16;
            float v[16];
            *(float4*)&v[0]  = *(const float4*)(xp);
            *(float4*)&v[4]  = *(const float4*)(xp + 4);
            *(float4*)&v[8]  = *(const float4*)(xp + 8);
            *(float4*)&v[12] = *(const float4*)(xp + 12);
            #pragma unroll
            for (int j = 0; j < 8; ++j) q[j] = pk2(v[2*j] * scale, v[2*j+1] * scale);
        } else {
            float s[16];
            #pragma unroll
            for (int j = 0; j < 16; ++j) s[j] = 0.0f;
            #pragma unroll
            for (int slot = 0; slot < NG; ++slot) {
                int gg = (slot == 0) ? g0 : (slot == 1) ? g1 : g2;
                if (gg != 0) {
                    const ushort* yp = ybin + ((size_t)row * NG + slot) * D + th * 16;
                    uint4 va = *(const uint4*)yp;
                    uint4 vb = *(const uint4*)(yp + 8);
                    unsigned w[8] = { va.x, va.y, va.z, va.w, vb.x, vb.y, vb.z, vb.w };
                    #pragma unroll
                    for (int j = 0; j < 8; ++j) {
                        s[2*j]   += bf2f((ushort)(w[j] & 0xFFFF));
                        s[2*j+1] += bf2f((ushort)(w[j] >> 16));
                    }
                }
            }
            #pragma unroll
            for (int j = 0; j < 8; ++j) {
                float lo = s[2*j],  hi = s[2*j+1];
                lo = ((lo >= 0.f) ? lo : 0.01f * lo) * scale;
                hi = ((hi >= 0.f) ? hi : 0.01f * hi) * scale;
                q[j] = pk2(lo, hi);
            }
        }
        int b0 = (t * 256 + (th * 2) * 16)     ^ ((t & 7) << 4);
        int b1 = (t * 256 + (th * 2 + 1) * 16) ^ ((t & 7) << 4);
        *(uint4*)(sXb + b0) = make_uint4(q[0], q[1], q[2], q[3]);
        *(uint4*)(sXb + b1) = make_uint4(q[4], q[5], q[6], q[7]);
    }
    __syncthreads();   // also drains vmcnt for global_load_lds

    const int g = lane >> 4, l15 = lane & 15;
    f32x4 acc00 = {0.f,0.f,0.f,0.f}, acc01 = {0.f,0.f,0.f,0.f};
    f32x4 acc10 = {0.f,0.f,0.f,0.f}, acc11 = {0.f,0.f,0.f,0.f};

    #pragma unroll
    for (int ks = 0; ks < 4; ++ks) {
        const int kb = ks * 64 + g * 16;
        int c0 = wave * 32 + l15, c1 = c0 + 16;
        short8 a0 = *(const short8*)(sWb + ((c0 * 256 + kb) ^ ((c0 & 7) << 4)));
        short8 a1 = *(const short8*)(sWb + ((c1 * 256 + kb) ^ ((c1 & 7) << 4)));
        int t0 = l15, t1 = l15 + 16;
        short8 b0 = *(const short8*)(sXb + ((t0 * 256 + kb) ^ ((t0 & 7) << 4)));
        short8 b1 = *(const short8*)(sXb + ((t1 * 256 + kb) ^ ((t1 & 7) << 4)));
        acc00 = __builtin_amdgcn_mfma_f32_16x16x32_bf16(a0, b0, acc00, 0, 0, 0);
        acc01 = __builtin_amdgcn_mfma_f32_16x16x32_bf16(a0, b1, acc01, 0, 0, 0);
        acc10 = __builtin_amdgcn_mfma_f32_16x16x32_bf16(a1, b0, acc10, 0, 0, 0);
        acc11 = __builtin_amdgcn_mfma_f32_16x16x32_bf16(a1, b1, acc11, 0, 0, 0);
    }

    #pragma unroll
    for (int n = 0; n < 2; ++n) {
        int tok = n * 16 + l15;
        if (tok < nt) {
            int bg = pair_bg[start + tok];
            ushort* dst = ydst + (size_t)bg * D + wave * 32 + g * 4;
            f32x4 v0 = (n == 0) ? acc00 : acc01;
            f32x4 v1 = (n == 0) ? acc10 : acc11;
            ushort4 p0 = { f2bf(v0[0]), f2bf(v0[1]), f2bf(v0[2]), f2bf(v0[3]) };
            ushort4 p1 = { f2bf(v1[0]), f2bf(v1[1]), f2bf(v1[2]), f2bf(v1[3]) };
            *(ushort4*)(dst)      = p0;
            *(ushort4*)(dst + 16) = p1;
        }
    }
}

static __device__ __forceinline__ void final_unit(
    int gid, const ushort* __restrict__ yb2, const int* __restrict__ genres,
    float* __restrict__ out)
{
    int b = gid >> 4, c8 = (gid & 15) * 8;
    int g0 = genres[b * NG + 0];
    int g1 = genres[b * NG + 1];
    int g2 = genres[b * NG + 2];

    float s[8] = {0,0,0,0,0,0,0,0};
    #pragma unroll
    for (int slot = 0; slot < NG; ++slot) {
        int g = (slot == 0) ? g0 : (slot == 1) ? g1 : g2;
        if (g != 0) {
            uint4 v = *(const uint4*)&yb2[((size_t)b * NG + slot) * D + c8];
            const unsigned w[4] = { v.x, v.y, v.z, v.w };
            #pragma unroll
            for (int j = 0; j < 4; ++j) {
                s[2*j]   += bf2f((ushort)(w[j] & 0xFFFF));
                s[2*j+1] += bf2f((ushort)(w[j] >> 16));
            }
        }
    }
    float r[8];
    #pragma unroll
    for (int j = 0; j < 8; ++j)
        r[j] = (s[j] >= 0.f) ? s[j] : 0.01f * s[j];
    float4 lo = { r[0], r[1], r[2], r[3] };
    float4 hi = { r[4], r[5], r[6], r[7] };
    *(float4*)&out[(size_t)b * D + c8]     = lo;
    *(float4*)&out[(size_t)b * D + c8 + 4] = hi;
}

// ================= cooperative mega-kernel =================
// 40960 B LDS -> 4 blocks/CU (160 KiB exactly); launch_bounds(256,4) caps
// VGPR <= 128 so 4 blocks/CU holds. 5 phases, 4 grid syncs.
__global__ __launch_bounds__(256, 4) void moe_mega_kernel(
    const float* __restrict__ x, const int* __restrict__ genres,
    const float* __restrict__ W0, const float* __restrict__ W1,
    float* __restrict__ out,
    int* __restrict__ nTiles, int4* __restrict__ tileInfo,
    int* __restrict__ hist_pb, int* __restrict__ pair_bg,
    ushort* __restrict__ Wt0, ushort* __restrict__ Wt1,
    ushort* __restrict__ yb, ushort* __restrict__ yb2)
{
    cg::grid_group gg = cg::this_grid();
    __shared__ __align__(16) char smem[40960];
    const int tid = threadIdx.x, bid = blockIdx.x, nb = gridDim.x;

    // Phase A: W transpose (128 units) + per-block hist (96 units)
    for (int u = bid; u < 128 + NHB; u += nb) {
        __syncthreads();
        if (u < 128) transpose_unit(u, tid, smem, W0, W1, Wt0, Wt1);
        else         hist_unit(u - 128, tid, smem, genres, hist_pb);
    }
    gg.sync();

    // Phase B: scatter + tile build
    for (int p = bid; p < NHB; p += nb) {
        __syncthreads();
        scatter_unit(p, tid, smem, genres, hist_pb, pair_bg, nTiles, tileInfo);
    }
    gg.sync();

    const int ntl = *nTiles;
    char* sWb = smem;
    char* sXb = smem + 32768;

    // Phase C: GEMM layer 1
    for (int t = bid; t < ntl; t += nb) {
        __syncthreads();
        int4 ti = tileInfo[t];
        gemm_tile_body<1>(sWb, sXb, x, nullptr, genres, Wt0, pair_bg,
                          ti.x, ti.y, ti.z, yb, tid);
    }
    gg.sync();

    // Phase D: GEMM layer 2 (fused layer-1 combine in staging)
    for (int t = bid; t < ntl; t += nb) {
        __syncthreads();
        int4 ti = tileInfo[t];
        gemm_tile_body<2>(sWb, sXb, nullptr, yb, genres, Wt1, pair_bg,
                          ti.x, ti.y, ti.z, yb2, tid);
    }
    gg.sync();

    // Phase E: final combine -> f32 out
    for (int u = bid; u < NFIN; u += nb)
        final_unit(u * 256 + tid, yb2, genres, out);
}

// ================= standalone fallback chain (round-5 path) =================
__global__ __launch_bounds__(256) void moe_prep_kernel(
    const float* __restrict__ W0, const float* __restrict__ W1,
    const int* __restrict__ genres, ushort* __restrict__ Wt0,
    ushort* __restrict__ Wt1, int* __restrict__ hist_pb)
{
    __shared__ __align__(16) char smem[17536];
    const int bid = blockIdx.x, tid = threadIdx.x;
    if (bid < 128) transpose_unit(bid, tid, smem, W0, W1, Wt0, Wt1);
    else           hist_unit(bid - 128, tid, smem, genres, hist_pb);
}

__global__ __launch_bounds__(256) void moe_scatter_kernel(
    const int* __restrict__ genres, const int* __restrict__ hist_pb,
    int* __restrict__ pair_bg, int* __restrict__ nTiles,
    int4* __restrict__ tileInfo)
{
    __shared__ __align__(16) char smem[256];
    scatter_unit(blockIdx.x, threadIdx.x, smem, genres, hist_pb, pair_bg,
                 nTiles, tileInfo);
}

__global__ __launch_bounds__(256, 4) void moe_gemm1_kernel(
    const float* __restrict__ x, const int* __restrict__ genres,
    const ushort* __restrict__ Wt, const int* __restrict__ pair_bg,
    const int4* __restrict__ tileInfo, const int* __restrict__ nTiles,
    ushort* __restrict__ yb)
{
    if ((int)blockIdx.x >= *nTiles) return;
    __shared__ __align__(16) char smem[40960];
    int4 ti = tileInfo[blockIdx.x];
    gemm_tile_body<1>(smem, smem + 32768, x, nullptr, genres, Wt, pair_bg,
                      ti.x, ti.y, ti.z, yb, threadIdx.x);
}

__global__ __launch_bounds__(256, 4) void moe_gemm2_kernel(
    const ushort* __restrict__ yb, const int* __restrict__ genres,
    const ushort* __restrict__ Wt, const int* __restrict__ pair_bg,
    const int4* __restrict__ tileInfo, const int* __restrict__ nTiles,
    ushort* __restrict__ yb2)
{
    if ((int)blockIdx.x >= *nTiles) return;
    __shared__ __align__(16) char smem[40960];
    int4 ti = tileInfo[blockIdx.x];
    gemm_tile_body<2>(smem, smem + 32768, nullptr, yb, genres, Wt, pair_bg,
                      ti.x, ti.y, ti.z, yb2, threadIdx.x);
}

__global__ __launch_bounds__(256) void moe_final_kernel(
    const ushort* __restrict__ yb2, const int* __restrict__ genres,
    float* __restrict__ out)
{
    final_unit(blockIdx.x * 256 + threadIdx.x, yb2, genres, out);
}

// round-0 per-token fallback if ws too small
__global__ __launch_bounds__(128) void moe_layer_kernel(
    const float* __restrict__ x, const int* __restrict__ genres,
    const float* __restrict__ W, float* __restrict__ out)
{
    const int b = blockIdx.x;
    const int o = threadIdx.x;
    __shared__ float xs[D];
    xs[o] = x[(size_t)b * D + o];
    __syncthreads();
    int e0 = genres[b * NG + 0], e1 = genres[b * NG + 1], e2 = genres[b * NG + 2];
    float acc = 0.0f; int cnt = 0;
    #pragma unroll
    for (int g = 0; g < NG; ++g) {
        int e = (g == 0) ? e0 : (g == 1) ? e1 : e2;
        if (e != 0) {
            ++cnt;
            const float* We = W + (size_t)e * D * D + o;
            float a = 0.0f;
            #pragma unroll 8
            for (int i = 0; i < D; ++i) a = fmaf(xs[i], We[(size_t)i * D], a);
            acc += a;
        }
    }
    float r = (cnt > 0) ? (acc / (float)cnt) : 0.0f;
    out[(size_t)b * D + o] = (r >= 0.0f) ? r : 0.01f * r;
}

extern "C" void kernel_launch(void* const* d_in, const int* in_sizes, int n_in,
                              void* d_out, int out_size, void* d_ws, size_t ws_size,
                              hipStream_t stream)
{
    const float* x      = (const float*)d_in[0];
    const int*   genres = (const int*)d_in[1];
    const float* W0     = (const float*)d_in[2];
    const float* W1     = (const float*)d_in[3];
    float*       out    = (float*)d_out;

    if (ws_size < WS_REQUIRED) {
        moe_layer_kernel<<<BATCH, D, 0, stream>>>(x,   genres, W0, out);
        moe_layer_kernel<<<BATCH, D, 0, stream>>>(out, genres, W1, out);
        return;
    }

    char* ws = (char*)d_ws;
    int*    nTiles   = (int*)(ws + OFF_NT);
    int4*   tileInfo = (int4*)(ws + OFF_TILES);
    int*    hist_pb  = (int*)(ws + OFF_HISTPB);
    int*    pair_bg  = (int*)(ws + OFF_PAIR);
    ushort* Wt0      = (ushort*)(ws + OFF_WT0);
    ushort* Wt1      = (ushort*)(ws + OFF_WT1);
    ushort* yb       = (ushort*)(ws + OFF_YB);
    ushort* yb2      = (ushort*)(ws + OFF_YB2);

    // grid for cooperative launch: min(MAXT, occupancy-limited co-residency)
    int occ = 0;
    hipError_t oe = hipOccupancyMaxActiveBlocksPerMultiprocessor(
        &occ, reinterpret_cast<const void*>(&moe_mega_kernel), 256, 0);
    int numCU = 256;
    {
        int dev = 0;
        if (hipGetDevice(&dev) == hipSuccess) {
            hipDeviceProp_t prop;
            if (hipGetDeviceProperties(&prop, dev) == hipSuccess &&
                prop.multiProcessorCount > 0)
                numCU = prop.multiProcessorCount;
        }
    }
    if (oe != hipSuccess || occ <= 0) occ = 3;   // conservative fallback
    int grid = occ * numCU;
    if (grid > MAXT) grid = MAXT;
    if (grid < 1) grid = 1;

    void* args[] = { (void*)&x, (void*)&genres, (void*)&W0, (void*)&W1,
                     (void*)&out, (void*)&nTiles, (void*)&tileInfo,
                     (void*)&hist_pb, (void*)&pair_bg, (void*)&Wt0,
                     (void*)&Wt1, (void*)&yb, (void*)&yb2 };
    hipError_t err = hipLaunchCooperativeKernel(
        reinterpret_cast<void*>(&moe_mega_kernel),
        dim3(grid), dim3(256), args, 0, stream);

    if (err != hipSuccess) {
        // fallback: proven 5-kernel chain
        moe_prep_kernel<<<128 + NHB, 256, 0, stream>>>(W0, W1, genres,
                                                       Wt0, Wt1, hist_pb);
        moe_scatter_kernel<<<NHB, 256, 0, stream>>>(genres, hist_pb, pair_bg,
                                                    nTiles, tileInfo);
        moe_gemm1_kernel<<<MAXT, 256, 0, stream>>>(x, genres, Wt0, pair_bg,
                                                   tileInfo, nTiles, yb);
        moe_gemm2_kernel<<<MAXT, 256, 0, stream>>>(yb, genres, Wt1, pair_bg,
                                                   tileInfo, nTiles, yb2);
        moe_final_kernel<<<NFIN, 256, 0, stream>>>(yb2, genres, out);
    }
}

// Round 9
// 33.480 us; speedup vs baseline: 8.2584x; 8.2584x over previous
//
#include <hip/hip_runtime.h>

#define BATCH 8192
#define NG 3
#define NE 32
#define D 128
#define NPAIR (BATCH * NG)            // 24576
#define TILE 32                       // tokens per MFMA sub-tile
#define CHUNK 2048                    // pairs scanned per block
#define NCHUNK (NPAIR / CHUNK)        // 12
#define NFIN (BATCH * 16 / 256)       // 512 final blocks

typedef __attribute__((ext_vector_type(8))) short short8;
typedef __attribute__((ext_vector_type(4))) float f32x4;

// ---------------- workspace layout (bytes) ----------------
#define OFF_YB   0                                      // bf16 [NPAIR][D], 6 MB
#define OFF_YB2  ((size_t)NPAIR * D * 2)                // bf16 [NPAIR][D], 6 MB
#define WS_REQUIRED (OFF_YB2 + (size_t)NPAIR * D * 2)   // ~12.6 MB

static __device__ __forceinline__ ushort f2bf(float f) {
    unsigned b = __float_as_uint(f);
    unsigned r = (b + 0x7FFFu + ((b >> 16) & 1u)) >> 16;   // RNE
    return (ushort)r;
}
static __device__ __forceinline__ float bf2f(ushort u) {
    return __uint_as_float(((unsigned)u) << 16);
}
static __device__ __forceinline__ unsigned pk2(float lo, float hi) {
    return (unsigned)f2bf(lo) | ((unsigned)f2bf(hi) << 16);
}

// ================= self-dispatching grouped GEMM =================
// Block (chunk, e): scan 2048-pair slice for genre==e, compact pair ids to
// LDS, stage W[e] (f32 -> bf16, transpose, XOR-swizzle) once, then loop
// 32-token sub-tiles: stage x (LAYER 1: f32 * 1/cnt; LAYER 2: fused
// lrelu(sum yb slots)/cnt), 16x mfma_f32_16x16x32_bf16, write ydst by pair id.
// LDS: 32K (sW) + 8K (sX) + 8K (list) = 48.5K -> 3 blocks/CU.
template<int LAYER>
static __device__ __forceinline__ void gemm_body(
    const float* __restrict__ x, const ushort* __restrict__ ybin,
    const int* __restrict__ genres, const float* __restrict__ W,
    ushort* __restrict__ ydst)
{
    const int e = blockIdx.y + 1;          // experts 1..31 (0 = padding)
    const int pbase = blockIdx.x * CHUNK;

    __shared__ ushort sW[D * D];           // swizzled [col][k] bf16
    __shared__ ushort sX[TILE * D];
    __shared__ int list[CHUNK];
    __shared__ int scnt;

    const int tid = threadIdx.x;
    if (tid == 0) scnt = 0;
    __syncthreads();

    // build match list (order scheduling-dependent; output invariant since
    // each pair's value depends only on (token, expert) and is written by id)
    #pragma unroll
    for (int i = 0; i < CHUNK / 256; ++i) {
        int p = pbase + i * 256 + tid;
        if (genres[p] == e) {
            int idx = atomicAdd(&scnt, 1);
            list[idx] = p;
        }
    }

    // stage W[e]: sW[col][k] = bf16(W[k][col]), XOR-swizzled rows.
    // 16 iters x 256 thr x 4 k-entries = 16384 = D*D (full matrix).
    // Each iter: 4 coalesced f32 col-reads -> 2 packed b32 -> one uint2 write
    // (swizzle XOR touches only bits 4..6, so 8 B alignment is preserved).
    const float* Ws = W + (size_t)e * D * D;
    char* sWb = (char*)sW;
    #pragma unroll
    for (int i = 0; i < 16; ++i) {
        int idx = i * 256 + tid;           // 0..4095
        int c = idx & 127;                 // col
        int k4 = idx >> 7;                 // 0..31 -> k = 4*k4
        float a0 = Ws[(size_t)(4 * k4 + 0) * D + c];
        float a1 = Ws[(size_t)(4 * k4 + 1) * D + c];
        float a2 = Ws[(size_t)(4 * k4 + 2) * D + c];
        float a3 = Ws[(size_t)(4 * k4 + 3) * D + c];
        int byteoff = (c * 256 + k4 * 8) ^ ((c & 7) << 4);
        uint2 q = { pk2(a0, a1), pk2(a2, a3) };
        *(uint2*)(sWb + byteoff) = q;
    }
    __syncthreads();

    const int ntotal = scnt;
    const int wave = tid >> 6, lane = tid & 63;
    const int g = lane >> 4, l15 = lane & 15;
    char* sXb = (char*)sX;

    for (int t0 = 0; t0 < ntotal; t0 += TILE) {
        const int nt = min(TILE, ntotal - t0);
        __syncthreads();                   // sX safe to overwrite

        // stage x: 8 threads per token, 16 cols each
        {
            const int t = tid >> 3, th = tid & 7;
            int p = list[t0 + ((t < nt) ? t : 0)];
            int row = p / NG;
            int g0 = genres[row * NG + 0];
            int g1 = genres[row * NG + 1];
            int g2 = genres[row * NG + 2];
            int cnt = (g0 != 0) + (g1 != 0) + (g2 != 0);
            float scale = 1.0f / (float)((cnt > 0) ? cnt : 1);
            unsigned q[8];
            if (LAYER == 1) {
                const float* xp = x + (size_t)row * D + th * 16;
                float v[16];
                *(float4*)&v[0]  = *(const float4*)(xp);
                *(float4*)&v[4]  = *(const float4*)(xp + 4);
                *(float4*)&v[8]  = *(const float4*)(xp + 8);
                *(float4*)&v[12] = *(const float4*)(xp + 12);
                #pragma unroll
                for (int j = 0; j < 8; ++j)
                    q[j] = pk2(v[2*j] * scale, v[2*j+1] * scale);
            } else {
                float s[16];
                #pragma unroll
                for (int j = 0; j < 16; ++j) s[j] = 0.0f;
                #pragma unroll
                for (int slot = 0; slot < NG; ++slot) {
                    int gg = (slot == 0) ? g0 : (slot == 1) ? g1 : g2;
                    if (gg != 0) {
                        const ushort* yp = ybin + ((size_t)row * NG + slot) * D + th * 16;
                        uint4 va = *(const uint4*)yp;
                        uint4 vb = *(const uint4*)(yp + 8);
                        unsigned w[8] = { va.x, va.y, va.z, va.w,
                                          vb.x, vb.y, vb.z, vb.w };
                        #pragma unroll
                        for (int j = 0; j < 8; ++j) {
                            s[2*j]   += bf2f((ushort)(w[j] & 0xFFFF));
                            s[2*j+1] += bf2f((ushort)(w[j] >> 16));
                        }
                    }
                }
                #pragma unroll
                for (int j = 0; j < 8; ++j) {
                    float lo = s[2*j],  hi = s[2*j+1];
                    lo = ((lo >= 0.f) ? lo : 0.01f * lo) * scale;
                    hi = ((hi >= 0.f) ? hi : 0.01f * hi) * scale;
                    q[j] = pk2(lo, hi);
                }
            }
            int b0 = (t * 256 + (th * 2) * 16)     ^ ((t & 7) << 4);
            int b1 = (t * 256 + (th * 2 + 1) * 16) ^ ((t & 7) << 4);
            *(uint4*)(sXb + b0) = make_uint4(q[0], q[1], q[2], q[3]);
            *(uint4*)(sXb + b1) = make_uint4(q[4], q[5], q[6], q[7]);
        }
        __syncthreads();

        f32x4 acc00 = {0.f,0.f,0.f,0.f}, acc01 = {0.f,0.f,0.f,0.f};
        f32x4 acc10 = {0.f,0.f,0.f,0.f}, acc11 = {0.f,0.f,0.f,0.f};

        #pragma unroll
        for (int ks = 0; ks < 4; ++ks) {
            const int kb = ks * 64 + g * 16;
            int c0 = wave * 32 + l15, c1 = c0 + 16;
            short8 a0 = *(const short8*)(sWb + ((c0 * 256 + kb) ^ ((c0 & 7) << 4)));
            short8 a1 = *(const short8*)(sWb + ((c1 * 256 + kb) ^ ((c1 & 7) << 4)));
            int t0l = l15, t1l = l15 + 16;
            short8 b0 = *(const short8*)(sXb + ((t0l * 256 + kb) ^ ((t0l & 7) << 4)));
            short8 b1 = *(const short8*)(sXb + ((t1l * 256 + kb) ^ ((t1l & 7) << 4)));
            acc00 = __builtin_amdgcn_mfma_f32_16x16x32_bf16(a0, b0, acc00, 0, 0, 0);
            acc01 = __builtin_amdgcn_mfma_f32_16x16x32_bf16(a0, b1, acc01, 0, 0, 0);
            acc10 = __builtin_amdgcn_mfma_f32_16x16x32_bf16(a1, b0, acc10, 0, 0, 0);
            acc11 = __builtin_amdgcn_mfma_f32_16x16x32_bf16(a1, b1, acc11, 0, 0, 0);
        }

        #pragma unroll
        for (int n = 0; n < 2; ++n) {
            int tok = n * 16 + l15;
            if (tok < nt) {
                int p = list[t0 + tok];
                ushort* dst = ydst + (size_t)p * D + wave * 32 + g * 4;
                f32x4 v0 = (n == 0) ? acc00 : acc01;
                f32x4 v1 = (n == 0) ? acc10 : acc11;
                ushort4 p0 = { f2bf(v0[0]), f2bf(v0[1]), f2bf(v0[2]), f2bf(v0[3]) };
                ushort4 p1 = { f2bf(v1[0]), f2bf(v1[1]), f2bf(v1[2]), f2bf(v1[3]) };
                *(ushort4*)(dst)      = p0;
                *(ushort4*)(dst + 16) = p1;
            }
        }
    }
}

__global__ __launch_bounds__(256, 3) void moe_gemm1_kernel(
    const float* __restrict__ x, const int* __restrict__ genres,
    const float* __restrict__ W0, ushort* __restrict__ yb)
{
    gemm_body<1>(x, nullptr, genres, W0, yb);
}

__global__ __launch_bounds__(256, 3) void moe_gemm2_kernel(
    const ushort* __restrict__ yb, const int* __restrict__ genres,
    const float* __restrict__ W1, ushort* __restrict__ yb2)
{
    gemm_body<2>(nullptr, yb, genres, W1, yb2);
}

// ---------------- final: out[b] = lrelu(sum_live yb2[b,slot]) f32 ----------------
__global__ __launch_bounds__(256) void moe_final_kernel(
    const ushort* __restrict__ yb2, const int* __restrict__ genres,
    float* __restrict__ out)
{
    int gid = blockIdx.x * 256 + threadIdx.x;   // BATCH*16 chunks of 8
    int b = gid >> 4, c8 = (gid & 15) * 8;
    int g0 = genres[b * NG + 0];
    int g1 = genres[b * NG + 1];
    int g2 = genres[b * NG + 2];

    float s[8] = {0,0,0,0,0,0,0,0};
    #pragma unroll
    for (int slot = 0; slot < NG; ++slot) {
        int g = (slot == 0) ? g0 : (slot == 1) ? g1 : g2;
        if (g != 0) {
            uint4 v = *(const uint4*)&yb2[((size_t)b * NG + slot) * D + c8];
            const unsigned w[4] = { v.x, v.y, v.z, v.w };
            #pragma unroll
            for (int j = 0; j < 4; ++j) {
                s[2*j]   += bf2f((ushort)(w[j] & 0xFFFF));
                s[2*j+1] += bf2f((ushort)(w[j] >> 16));
            }
        }
    }
    float r[8];
    #pragma unroll
    for (int j = 0; j < 8; ++j)
        r[j] = (s[j] >= 0.f) ? s[j] : 0.01f * s[j];
    float4 lo = { r[0], r[1], r[2], r[3] };
    float4 hi = { r[4], r[5], r[6], r[7] };
    *(float4*)&out[(size_t)b * D + c8]     = lo;
    *(float4*)&out[(size_t)b * D + c8 + 4] = hi;
}

// ---------------- round-0 per-token fallback if ws too small ----------------
__global__ __launch_bounds__(128) void moe_layer_kernel(
    const float* __restrict__ x, const int* __restrict__ genres,
    const float* __restrict__ W, float* __restrict__ out)
{
    const int b = blockIdx.x;
    const int o = threadIdx.x;
    __shared__ float xs[D];
    xs[o] = x[(size_t)b * D + o];
    __syncthreads();
    int e0 = genres[b * NG + 0], e1 = genres[b * NG + 1], e2 = genres[b * NG + 2];
    float acc = 0.0f; int cnt = 0;
    #pragma unroll
    for (int g = 0; g < NG; ++g) {
        int e = (g == 0) ? e0 : (g == 1) ? e1 : e2;
        if (e != 0) {
            ++cnt;
            const float* We = W + (size_t)e * D * D + o;
            float a = 0.0f;
            #pragma unroll 8
            for (int i = 0; i < D; ++i) a = fmaf(xs[i], We[(size_t)i * D], a);
            acc += a;
        }
    }
    float r = (cnt > 0) ? (acc / (float)cnt) : 0.0f;
    out[(size_t)b * D + o] = (r >= 0.0f) ? r : 0.01f * r;
}

extern "C" void kernel_launch(void* const* d_in, const int* in_sizes, int n_in,
                              void* d_out, int out_size, void* d_ws, size_t ws_size,
                              hipStream_t stream)
{
    const float* x      = (const float*)d_in[0];
    const int*   genres = (const int*)d_in[1];
    const float* W0     = (const float*)d_in[2];
    const float* W1     = (const float*)d_in[3];
    float*       out    = (float*)d_out;

    if (ws_size < WS_REQUIRED) {
        moe_layer_kernel<<<BATCH, D, 0, stream>>>(x,   genres, W0, out);
        moe_layer_kernel<<<BATCH, D, 0, stream>>>(out, genres, W1, out);
        return;
    }

    char* ws = (char*)d_ws;
    ushort* yb  = (ushort*)(ws + OFF_YB);
    ushort* yb2 = (ushort*)(ws + OFF_YB2);

    dim3 ggrid(NCHUNK, NE - 1);   // 12 x 31 = 372 blocks
    moe_gemm1_kernel<<<ggrid, 256, 0, stream>>>(x, genres, W0, yb);
    moe_gemm2_kernel<<<ggrid, 256, 0, stream>>>(yb, genres, W1, yb2);
    moe_final_kernel<<<NFIN, 256, 0, stream>>>(yb2, genres, out);
}

// Round 10
// 31.195 us; speedup vs baseline: 8.8634x; 1.0733x over previous
//
#include <hip/hip_runtime.h>

#define BATCH 8192
#define NG 3
#define NE 32
#define D 128
#define NPAIR (BATCH * NG)            // 24576
#define TILE 32                       // tokens per MFMA sub-tile
#define CHUNK 2048                    // pairs scanned per block
#define NCHUNK (NPAIR / CHUNK)        // 12
#define NFIN (BATCH * 16 / 256)       // 512 final blocks

typedef __attribute__((ext_vector_type(8))) short short8;
typedef __attribute__((ext_vector_type(4))) float f32x4;

// ---------------- workspace layout (bytes) ----------------
#define OFF_YB   0                                      // bf16 [NPAIR][D], 6 MB
#define OFF_YB2  ((size_t)NPAIR * D * 2)                // bf16 [NPAIR][D], 6 MB
#define WS_REQUIRED (OFF_YB2 + (size_t)NPAIR * D * 2)   // ~12.6 MB

static __device__ __forceinline__ ushort f2bf(float f) {
    unsigned b = __float_as_uint(f);
    unsigned r = (b + 0x7FFFu + ((b >> 16) & 1u)) >> 16;   // RNE
    return (ushort)r;
}
static __device__ __forceinline__ float bf2f(ushort u) {
    return __uint_as_float(((unsigned)u) << 16);
}
static __device__ __forceinline__ unsigned pk2(float lo, float hi) {
    return (unsigned)f2bf(lo) | ((unsigned)f2bf(hi) << 16);
}

// ================= self-dispatching grouped GEMM, column-split =================
// Block (chunk, hcol, e): scan 2048-pair slice for genre==e (int4 loads),
// compact pair ids to LDS, stage HALF of W[e] (cols [64*hcol,64*hcol+64),
// f32 -> bf16, transpose, XOR-swizzle; 16 KB), then loop 32-token sub-tiles:
// stage x (LAYER 1: f32 * 1/cnt; LAYER 2: fused lrelu(sum yb slots)/cnt),
// 8 MFMA/wave, write ydst cols of this half by pair id.
// LDS: 16K (sW) + 8K (sX) + 8K (list) = 32.8K -> 4 blocks/CU, 16 waves/CU.
template<int LAYER>
static __device__ __forceinline__ void gemm_body(
    const float* __restrict__ x, const ushort* __restrict__ ybin,
    const int* __restrict__ genres, const float* __restrict__ W,
    ushort* __restrict__ ydst)
{
    const int bx = blockIdx.x;
    const int chunk = bx >> 1, hcol = bx & 1;
    const int e = blockIdx.y + 1;          // experts 1..31 (0 = padding)
    const int pbase = chunk * CHUNK;

    __shared__ ushort sW[64 * D];          // swizzled [col_local][k], 16 KB
    __shared__ ushort sX[TILE * D];        // 8 KB
    __shared__ int list[CHUNK];            // 8 KB
    __shared__ int scnt;

    const int tid = threadIdx.x;
    if (tid == 0) scnt = 0;
    __syncthreads();

    // build match list via int4 scan (order scheduling-dependent; output
    // invariant since each pair's value depends only on (token, expert)
    // and is written by pair id)
    const int4* g4 = (const int4*)(genres + pbase);
    #pragma unroll
    for (int i = 0; i < CHUNK / 1024; ++i) {
        int4 gv = g4[i * 256 + tid];
        int p = pbase + (i * 256 + tid) * 4;
        if (gv.x == e) list[atomicAdd(&scnt, 1)] = p + 0;
        if (gv.y == e) list[atomicAdd(&scnt, 1)] = p + 1;
        if (gv.z == e) list[atomicAdd(&scnt, 1)] = p + 2;
        if (gv.w == e) list[atomicAdd(&scnt, 1)] = p + 3;
    }
    __syncthreads();
    const int ntotal = scnt;
    if (ntotal == 0) return;

    // stage W half: sW[c][k] = bf16(W[k][64*hcol + c]), XOR-swizzled rows.
    // 8 iters x 256 thr x 4 k-entries = 8192 = 64*128 (full half).
    const float* Ws = W + (size_t)e * D * D + hcol * 64;
    char* sWb = (char*)sW;
    #pragma unroll
    for (int i = 0; i < 8; ++i) {
        int idx = i * 256 + tid;           // 0..2047
        int c = idx & 63;                  // local col
        int k4 = idx >> 6;                 // 0..31 -> k = 4*k4
        float a0 = Ws[(size_t)(4 * k4 + 0) * D + c];
        float a1 = Ws[(size_t)(4 * k4 + 1) * D + c];
        float a2 = Ws[(size_t)(4 * k4 + 2) * D + c];
        float a3 = Ws[(size_t)(4 * k4 + 3) * D + c];
        int byteoff = (c * 256 + k4 * 8) ^ ((c & 7) << 4);
        uint2 q = { pk2(a0, a1), pk2(a2, a3) };
        *(uint2*)(sWb + byteoff) = q;
    }
    // sW-write/read barrier provided by the loop's leading __syncthreads()

    const int wave = tid >> 6, lane = tid & 63;
    const int g = lane >> 4, l15 = lane & 15;
    const int colb = wave * 16;            // local col base of this wave
    char* sXb = (char*)sX;

    for (int t0 = 0; t0 < ntotal; t0 += TILE) {
        const int nt = min(TILE, ntotal - t0);
        __syncthreads();                   // sW ready / sX safe to overwrite

        // stage x: 8 threads per token, 16 cols each (full K=128 needed)
        {
            const int t = tid >> 3, th = tid & 7;
            int p = list[t0 + ((t < nt) ? t : 0)];
            int row = p / NG;
            int g0 = genres[row * NG + 0];
            int g1 = genres[row * NG + 1];
            int g2 = genres[row * NG + 2];
            int cnt = (g0 != 0) + (g1 != 0) + (g2 != 0);
            float scale = 1.0f / (float)((cnt > 0) ? cnt : 1);
            unsigned q[8];
            if (LAYER == 1) {
                const float* xp = x + (size_t)row * D + th * 16;
                float v[16];
                *(float4*)&v[0]  = *(const float4*)(xp);
                *(float4*)&v[4]  = *(const float4*)(xp + 4);
                *(float4*)&v[8]  = *(const float4*)(xp + 8);
                *(float4*)&v[12] = *(const float4*)(xp + 12);
                #pragma unroll
                for (int j = 0; j < 8; ++j)
                    q[j] = pk2(v[2*j] * scale, v[2*j+1] * scale);
            } else {
                float s[16];
                #pragma unroll
                for (int j = 0; j < 16; ++j) s[j] = 0.0f;
                #pragma unroll
                for (int slot = 0; slot < NG; ++slot) {
                    int gg = (slot == 0) ? g0 : (slot == 1) ? g1 : g2;
                    if (gg != 0) {
                        const ushort* yp = ybin + ((size_t)row * NG + slot) * D + th * 16;
                        uint4 va = *(const uint4*)yp;
                        uint4 vb = *(const uint4*)(yp + 8);
                        unsigned w[8] = { va.x, va.y, va.z, va.w,
                                          vb.x, vb.y, vb.z, vb.w };
                        #pragma unroll
                        for (int j = 0; j < 8; ++j) {
                            s[2*j]   += bf2f((ushort)(w[j] & 0xFFFF));
                            s[2*j+1] += bf2f((ushort)(w[j] >> 16));
                        }
                    }
                }
                #pragma unroll
                for (int j = 0; j < 8; ++j) {
                    float lo = s[2*j],  hi = s[2*j+1];
                    lo = ((lo >= 0.f) ? lo : 0.01f * lo) * scale;
                    hi = ((hi >= 0.f) ? hi : 0.01f * hi) * scale;
                    q[j] = pk2(lo, hi);
                }
            }
            int b0 = (t * 256 + (th * 2) * 16)     ^ ((t & 7) << 4);
            int b1 = (t * 256 + (th * 2 + 1) * 16) ^ ((t & 7) << 4);
            *(uint4*)(sXb + b0) = make_uint4(q[0], q[1], q[2], q[3]);
            *(uint4*)(sXb + b1) = make_uint4(q[4], q[5], q[6], q[7]);
        }
        __syncthreads();

        f32x4 acc0 = {0.f,0.f,0.f,0.f}, acc1 = {0.f,0.f,0.f,0.f};

        #pragma unroll
        for (int ks = 0; ks < 4; ++ks) {
            const int kb = ks * 64 + g * 16;
            int c0 = colb + l15;           // local col 0..63
            short8 a0 = *(const short8*)(sWb + ((c0 * 256 + kb) ^ ((c0 & 7) << 4)));
            int t0l = l15, t1l = l15 + 16;
            short8 b0 = *(const short8*)(sXb + ((t0l * 256 + kb) ^ ((t0l & 7) << 4)));
            short8 b1 = *(const short8*)(sXb + ((t1l * 256 + kb) ^ ((t1l & 7) << 4)));
            acc0 = __builtin_amdgcn_mfma_f32_16x16x32_bf16(a0, b0, acc0, 0, 0, 0);
            acc1 = __builtin_amdgcn_mfma_f32_16x16x32_bf16(a0, b1, acc1, 0, 0, 0);
        }

        #pragma unroll
        for (int n = 0; n < 2; ++n) {
            int tok = n * 16 + l15;
            if (tok < nt) {
                int p = list[t0 + tok];
                ushort* dst = ydst + (size_t)p * D + hcol * 64 + colb + g * 4;
                f32x4 v = (n == 0) ? acc0 : acc1;
                ushort4 pq = { f2bf(v[0]), f2bf(v[1]), f2bf(v[2]), f2bf(v[3]) };
                *(ushort4*)dst = pq;
            }
        }
    }
}

__global__ __launch_bounds__(256, 4) void moe_gemm1_kernel(
    const float* __restrict__ x, const int* __restrict__ genres,
    const float* __restrict__ W0, ushort* __restrict__ yb)
{
    gemm_body<1>(x, nullptr, genres, W0, yb);
}

__global__ __launch_bounds__(256, 4) void moe_gemm2_kernel(
    const ushort* __restrict__ yb, const int* __restrict__ genres,
    const float* __restrict__ W1, ushort* __restrict__ yb2)
{
    gemm_body<2>(nullptr, yb, genres, W1, yb2);
}

// ---------------- final: out[b] = lrelu(sum_live yb2[b,slot]) f32 ----------------
__global__ __launch_bounds__(256) void moe_final_kernel(
    const ushort* __restrict__ yb2, const int* __restrict__ genres,
    float* __restrict__ out)
{
    int gid = blockIdx.x * 256 + threadIdx.x;   // BATCH*16 chunks of 8
    int b = gid >> 4, c8 = (gid & 15) * 8;
    int g0 = genres[b * NG + 0];
    int g1 = genres[b * NG + 1];
    int g2 = genres[b * NG + 2];

    float s[8] = {0,0,0,0,0,0,0,0};
    #pragma unroll
    for (int slot = 0; slot < NG; ++slot) {
        int g = (slot == 0) ? g0 : (slot == 1) ? g1 : g2;
        if (g != 0) {
            uint4 v = *(const uint4*)&yb2[((size_t)b * NG + slot) * D + c8];
            const unsigned w[4] = { v.x, v.y, v.z, v.w };
            #pragma unroll
            for (int j = 0; j < 4; ++j) {
                s[2*j]   += bf2f((ushort)(w[j] & 0xFFFF));
                s[2*j+1] += bf2f((ushort)(w[j] >> 16));
            }
        }
    }
    float r[8];
    #pragma unroll
    for (int j = 0; j < 8; ++j)
        r[j] = (s[j] >= 0.f) ? s[j] : 0.01f * s[j];
    float4 lo = { r[0], r[1], r[2], r[3] };
    float4 hi = { r[4], r[5], r[6], r[7] };
    *(float4*)&out[(size_t)b * D + c8]     = lo;
    *(float4*)&out[(size_t)b * D + c8 + 4] = hi;
}

// ---------------- round-0 per-token fallback if ws too small ----------------
__global__ __launch_bounds__(128) void moe_layer_kernel(
    const float* __restrict__ x, const int* __restrict__ genres,
    const float* __restrict__ W, float* __restrict__ out)
{
    const int b = blockIdx.x;
    const int o = threadIdx.x;
    __shared__ float xs[D];
    xs[o] = x[(size_t)b * D + o];
    __syncthreads();
    int e0 = genres[b * NG + 0], e1 = genres[b * NG + 1], e2 = genres[b * NG + 2];
    float acc = 0.0f; int cnt = 0;
    #pragma unroll
    for (int g = 0; g < NG; ++g) {
        int e = (g == 0) ? e0 : (g == 1) ? e1 : e2;
        if (e != 0) {
            ++cnt;
            const float* We = W + (size_t)e * D * D + o;
            float a = 0.0f;
            #pragma unroll 8
            for (int i = 0; i < D; ++i) a = fmaf(xs[i], We[(size_t)i * D], a);
            acc += a;
        }
    }
    float r = (cnt > 0) ? (acc / (float)cnt) : 0.0f;
    out[(size_t)b * D + o] = (r >= 0.0f) ? r : 0.01f * r;
}

extern "C" void kernel_launch(void* const* d_in, const int* in_sizes, int n_in,
                              void* d_out, int out_size, void* d_ws, size_t ws_size,
                              hipStream_t stream)
{
    const float* x      = (const float*)d_in[0];
    const int*   genres = (const int*)d_in[1];
    const float* W0     = (const float*)d_in[2];
    const float* W1     = (const float*)d_in[3];
    float*       out    = (float*)d_out;

    if (ws_size < WS_REQUIRED) {
        moe_layer_kernel<<<BATCH, D, 0, stream>>>(x,   genres, W0, out);
        moe_layer_kernel<<<BATCH, D, 0, stream>>>(out, genres, W1, out);
        return;
    }

    char* ws = (char*)d_ws;
    ushort* yb  = (ushort*)(ws + OFF_YB);
    ushort* yb2 = (ushort*)(ws + OFF_YB2);

    dim3 ggrid(NCHUNK * 2, NE - 1);   // (12 chunks x 2 col-halves) x 31 experts
    moe_gemm1_kernel<<<ggrid, 256, 0, stream>>>(x, genres, W0, yb);
    moe_gemm2_kernel<<<ggrid, 256, 0, stream>>>(yb, genres, W1, yb2);
    moe_final_kernel<<<NFIN, 256, 0, stream>>>(yb2, genres, out);
}